// Round 9
// baseline (611.472 us; speedup 1.0000x reference)
//
#include <hip/hip_runtime.h>

// AnchorTarget (pysot) for b=128, G=64, SCORE=25, A=5, STRIDE=8.
// Outputs concatenated as float32: cls(128,5,25,25) | bt(128,4,5,25,25) |
// bw(128,5,25,25) | max_ov(128,3125). Total 2,800,000 floats.
//
// Round 9: 2 dispatches. K3 fused into K2 via per-batch ticket chain:
//   K1: gtmax (r8's exact (I,D) column max) + zero ticket cells/flag.
//   K2: per-anchor row; ballot pos/neg counts; acquire/release ticket chain
//       gives each block its batch prefix -> caps applied in-kernel; batch
//       127's final ticket publishes pos_num (flag); bw written after a
//       short flag spin. Deadlock-safe: __launch_bounds__(256,8) caps VGPR
//       at 64 -> 8 blocks/CU -> 2048 resident slots >= 1664 blocks, so all
//       blocks are co-resident regardless of dispatch order.
// keep-test float equality protected by contract(off) in shared helpers.

namespace {
constexpr int B_   = 128;
constexpr int N_   = 3125;   // 25*25*5
constexpr int G_   = 64;
constexpr int A_   = 5;
constexpr int POSN = 16;
constexpr int TOTN = 64;

constexpr int CLS_OFF = 0;
constexpr int BT_OFF  = 400000;   // B*A*625
constexpr int BW_OFF  = 2000000;
constexpr int MO_OFF  = 2400000;
}

__device__ __forceinline__ float area_f(float x0, float y0, float x1, float y1) {
#pragma clang fp contract(off)
  return ((x1 - x0) + 1.0f) * ((y1 - y0) + 1.0f);
}

// inter and den=(aarea+garea)-inter with numpy's exact op order.
__device__ __forceinline__ float2 inter_den_f(float a0, float a1, float a2,
                                              float a3, float aarea, float g0,
                                              float g1, float g2, float g3,
                                              float garea) {
#pragma clang fp contract(off)
  float ix = (fminf(a2, g2) - fmaxf(a0, g0)) + 1.0f;
  float iy = (fminf(a3, g3) - fmaxf(a1, g1)) + 1.0f;
  ix = fmaxf(ix, 0.0f);
  iy = fmaxf(iy, 0.0f);
  float inter = ix * iy;
  float den = (aarea + garea) - inter;
  return make_float2(inter, den);
}

// exact real-quotient compare: In/Dn > Ic/Dc  (all D > 0; 24-bit products exact)
__device__ __forceinline__ bool q_gt(float In, float Dn, float Ic, float Dc) {
  return (double)In * (double)Dc > (double)Ic * (double)Dn;
}

// ---- K1: gt_max + packed per-(b,g) record; 2 cols/wave; init sync cells ---
// 4096 waves (1024 blk x 256 thr); wave w -> (b, g0) and (b, g0+1).
// gtpacked[(b*64+g)*8] = {x0,y0,x1,y1, garea, gtmax_adj, 0,0}
__global__ __launch_bounds__(256) void k1_gtmax(
    const float* __restrict__ gt,       // (128,64,4)
    const float* __restrict__ anchors,  // (3125,4)
    float* __restrict__ gtpacked,       // (128,64,8)
    int* __restrict__ cells,            // 128 x 16 ints: [0]=stage [1]=prefix
    int* __restrict__ poscnt) {
#pragma clang fp contract(off)
  if (blockIdx.x == 0) {
    if (threadIdx.x == 0) poscnt[0] = 0;
    if (threadIdx.x < B_) {
      cells[threadIdx.x * 16 + 0] = 0;
      cells[threadIdx.x * 16 + 1] = 0;
    }
  }

  const int t    = threadIdx.x;
  const int lane = t & 63;
  const int w    = blockIdx.x * 4 + (t >> 6);  // 0..4095
  const int p0   = w * 2;
  const int b    = p0 >> 6;
  const int g0   = p0 & 63;  // even

  const float4 gg0 = ((const float4*)gt)[b * G_ + g0];
  const float4 gg1 = ((const float4*)gt)[b * G_ + g0 + 1];
  const float ga0 = area_f(gg0.x, gg0.y, gg0.z, gg0.w);
  const float ga1 = area_f(gg1.x, gg1.y, gg1.z, gg1.w);

  // running max as (I,D): q = I/D; init 0/1 == iou 0 (iou >= 0 always)
  float I0 = 0.0f, D0 = 1.0f, I1 = 0.0f, D1 = 1.0f;
#pragma unroll 4
  for (int i = 0; i < 48; ++i) {
    const int n = i * 64 + lane;  // per-lane coalesced
    const float4 aa = ((const float4*)anchors)[n];
    const float aarea = area_f(aa.x, aa.y, aa.z, aa.w);
    const float2 e0 = inter_den_f(aa.x, aa.y, aa.z, aa.w, aarea,
                                  gg0.x, gg0.y, gg0.z, gg0.w, ga0);
    const float2 e1 = inter_den_f(aa.x, aa.y, aa.z, aa.w, aarea,
                                  gg1.x, gg1.y, gg1.z, gg1.w, ga1);
    if (q_gt(e0.x, e0.y, I0, D0)) { I0 = e0.x; D0 = e0.y; }
    if (q_gt(e1.x, e1.y, I1, D1)) { I1 = e1.x; D1 = e1.y; }
  }
  {
    const int n = 48 * 64 + lane;
    if (n < N_) {
      const float4 aa = ((const float4*)anchors)[n];
      const float aarea = area_f(aa.x, aa.y, aa.z, aa.w);
      const float2 e0 = inter_den_f(aa.x, aa.y, aa.z, aa.w, aarea,
                                    gg0.x, gg0.y, gg0.z, gg0.w, ga0);
      const float2 e1 = inter_den_f(aa.x, aa.y, aa.z, aa.w, aarea,
                                    gg1.x, gg1.y, gg1.z, gg1.w, ga1);
      if (q_gt(e0.x, e0.y, I0, D0)) { I0 = e0.x; D0 = e0.y; }
      if (q_gt(e1.x, e1.y, I1, D1)) { I1 = e1.x; D1 = e1.y; }
    }
  }
  // butterfly reduce under the exact-quotient total order (rounding monotone
  // => final rounded quotient == numpy's max of rounded quotients).
#pragma unroll
  for (int off = 32; off > 0; off >>= 1) {
    const float Io0 = __shfl_xor(I0, off, 64), Do0 = __shfl_xor(D0, off, 64);
    const float Io1 = __shfl_xor(I1, off, 64), Do1 = __shfl_xor(D1, off, 64);
    if (q_gt(Io0, Do0, I0, D0)) { I0 = Io0; D0 = Do0; }
    if (q_gt(Io1, Do1, I1, D1)) { I1 = Io1; D1 = Do1; }
  }
  if (lane == 0) {
    const float q0 = I0 / D0;  // IEEE f32 divide == numpy rounding
    const float q1 = I1 / D1;
    float4* gp = (float4*)gtpacked;
    gp[(b * G_ + g0) * 2 + 0] = gg0;
    gp[(b * G_ + g0) * 2 + 1] =
        make_float4(ga0, (q0 == 0.0f) ? 1e-5f : q0, 0.0f, 0.0f);
    gp[(b * G_ + g0 + 1) * 2 + 0] = gg1;
    gp[(b * G_ + g0 + 1) * 2 + 1] =
        make_float4(ga1, (q1 == 0.0f) ? 1e-5f : q1, 0.0f, 0.0f);
  }
}

// ---- K2: row + caps (ticket chain) + bw -----------------------------------
// Grid 1664 = 13 stripes x 128 batches; blk -> j = blk>>7, b = 127-(blk&127)
// so batch 127's chain links are earliest in each stripe.
__global__ __launch_bounds__(256, 8) void k2_fused(
    const float* __restrict__ anchors, const float* __restrict__ gtpacked,
    float* __restrict__ out, int* __restrict__ cells,
    int* __restrict__ poscnt) {
#pragma clang fp contract(off)
  const int blk  = blockIdx.x;
  const int b    = 127 - (blk & 127);
  const int j    = blk >> 7;          // 0..12
  const int t    = threadIdx.x;
  const int lane = t & 63;
  const int wid  = t >> 6;
  const int n    = j * 256 + t;
  const bool act = (n < N_);
  const int nc   = act ? n : 0;

  __shared__ int s_w[4];
  __shared__ int s_prev;
  __shared__ int s_pos;

  const float4 aa = ((const float4*)anchors)[nc];
  const float aw = (aa.z - aa.x) + 1.0f;
  const float ah = (aa.w - aa.y) + 1.0f;
  const float aarea = aw * ah;  // same op order as area_f

  const float4* __restrict__ gp = (const float4*)gtpacked;
  const int gbase = b * G_ * 2;  // block-uniform

  float best = -1.0f;
  int barg = 0;
  int keep = 0;
#pragma unroll 8
  for (int g = 0; g < G_; ++g) {
    const float4 gg = gp[gbase + g * 2 + 0];  // uniform -> s_load_dwordx4
    const float4 ge = gp[gbase + g * 2 + 1];  // uniform -> s_load_dwordx4
    const float2 e = inter_den_f(aa.x, aa.y, aa.z, aa.w, aarea,
                                 gg.x, gg.y, gg.z, gg.w, ge.x);
    const float v = e.x / e.y;             // IEEE, bit-exact vs numpy
    if (v > best) { best = v; barg = g; }  // first-occurrence argmax
    keep |= (v == ge.y);                   // bit-exact vs K1
  }

  int c = -1;
  if (best >= 0.6f) c = 1;
  if (best <= 0.3f) c = 0;
  if (keep) c = 1;
  if (!act) c = -2;  // excluded from counts

  // per-wave counts + O(1) lane prefixes
  const unsigned long long bal1 = __ballot(c == 1);
  const unsigned long long bal0 = __ballot(c == 0);
  const unsigned long long lt = (1ull << lane) - 1ull;
  const int pp = (int)__popcll(bal1 & lt);
  const int pn = (int)__popcll(bal0 & lt);
  if (lane == 0)
    s_w[wid] = ((int)__popcll(bal1) << 16) | (int)__popcll(bal0);
  __syncthreads();
  int wb = 0, btot = 0;
#pragma unroll
  for (int w2 = 0; w2 < 4; ++w2) {
    const int v = s_w[w2];
    btot += v;
    if (w2 < wid) wb += v;
  }

  // ticket chain: wait for stage[b]==j, grab batch prefix, pass it on.
  int* const cst = cells + b * 16;
  if (t == 0) {
    while (__hip_atomic_load(cst, __ATOMIC_ACQUIRE,
                             __HIP_MEMORY_SCOPE_AGENT) != j)
      __builtin_amdgcn_s_sleep(1);
    const int prev = __hip_atomic_load(cst + 1, __ATOMIC_RELAXED,
                                       __HIP_MEMORY_SCOPE_AGENT);
    s_prev = prev;
    __hip_atomic_store(cst + 1, prev + btot, __ATOMIC_RELAXED,
                       __HIP_MEMORY_SCOPE_AGENT);
    __hip_atomic_store(cst, j + 1, __ATOMIC_RELEASE,
                       __HIP_MEMORY_SCOPE_AGENT);
    if (b == B_ - 1 && j == 12) {
      const int tot = (prev + btot) >> 16;  // pre-cap positives of batch 127
      const int pos = (tot < POSN) ? tot : POSN;
      __hip_atomic_store(poscnt, 0x40000000 | pos, __ATOMIC_RELEASE,
                         __HIP_MEMORY_SCOPE_AGENT);
    }
  }
  __syncthreads();
  const int prev = s_prev;

  // caps: prefix-before >= cap  <=>  inclusive count > cap
  const int rp = (prev >> 16) + (wb >> 16) + pp;
  const int rn = (prev & 0xffff) + (wb & 0xffff) + pn;
  if (c == 1) {
    if (rp >= POSN) c = -1;
  } else if (c == 0) {
    if (rn >= TOTN) c = -1;
  }

  const int a = nc % A_;
  const int sp = nc / A_;  // spatial index in [0,625)

  if (act) {
    out[CLS_OFF + b * N_ + a * 625 + sp] = (float)c;
    out[MO_OFF + b * N_ + n] = best;

    const float4 mm = gp[gbase + barg * 2];  // divergent, L1/L2-hot
    const float gw = (mm.z - mm.x) + 1.0f;
    const float gh = (mm.w - mm.y) + 1.0f;
    const float acx = aa.x + 0.5f * aw;
    const float acy = aa.y + 0.5f * ah;
    const float gcx = mm.x + 0.5f * gw;
    const float gcy = mm.y + 0.5f * gh;
    float* __restrict__ out_bt = out + BT_OFF;
    const int btb = ((b * 4 + 0) * A_ + a) * 625 + sp;
    out_bt[btb + 0 * A_ * 625] = (gcx - acx) / aw;
    out_bt[btb + 1 * A_ * 625] = (gcy - acy) / ah;
    out_bt[btb + 2 * A_ * 625] = logf(gw / aw);
    out_bt[btb + 3 * A_ * 625] = logf(gh / ah);
  }

  // bw: needs batch-127's pos_num (flag usually already set — its chain links
  // are the earliest block in every stripe).
  if (t == 0) {
    int v;
    while ((v = __hip_atomic_load(poscnt, __ATOMIC_ACQUIRE,
                                  __HIP_MEMORY_SCOPE_AGENT)) == 0)
      __builtin_amdgcn_s_sleep(1);
    s_pos = v & 0xffff;
  }
  __syncthreads();
  if (act) {
    const float inv = 1.0f / (float)s_pos;  // inf if 0, matching ref
    out[BW_OFF + b * N_ + a * 625 + sp] = (c == 1) ? inv : 0.0f;
  }
}

extern "C" void kernel_launch(void* const* d_in, const int* in_sizes, int n_in,
                              void* d_out, int out_size, void* d_ws,
                              size_t ws_size, hipStream_t stream) {
  const float* gt = (const float*)d_in[0];       // (128,64,4)
  const float* anchors = (const float*)d_in[1];  // (3125,4)
  float* out = (float*)d_out;
  int* poscnt = (int*)d_ws;                      // [0] = flag|pos_num
  int* cells = (int*)d_ws + 64;                  // 128 x 16 ints (64B cells)
  float* gtpacked = (float*)d_ws + 64 + B_ * 16; // 128*64*8 floats, 16B-aligned

  // Stream ordering: K1 zeroes poscnt+cells & fills gtpacked; K2 consumes.
  k1_gtmax<<<1024, 256, 0, stream>>>(gt, anchors, gtpacked, cells, poscnt);
  k2_fused<<<13 * B_, 256, 0, stream>>>(anchors, gtpacked, out, cells, poscnt);
}

// Round 10
// 115.614 us; speedup vs baseline: 5.2889x; 5.2889x over previous
//
#include <hip/hip_runtime.h>

// AnchorTarget (pysot) for b=128, G=64, SCORE=25, A=5, STRIDE=8.
// Outputs concatenated as float32: cls(128,5,25,25) | bt(128,4,5,25,25) |
// bw(128,5,25,25) | max_ov(128,3125). Total 2,800,000 floats.
//
// Round 10: r8 structure (3 dispatches — r9's ticket-chain spin sync was a
// 5x regression: VALUBusy 4.7%, all waves polling device-scope atomics).
//  K2 change: wave-uniform zero-overlap skip — __ballot(inter>0)==0 branches
//  over the 10-inst IEEE div block (exact: 0/den == +0.0, and the else path
//  reproduces best/keep semantics bit-exactly). __logf in bt epilogue.
// keep-test float equality protected by contract(off) in shared helpers.

namespace {
constexpr int B_   = 128;
constexpr int N_   = 3125;   // 25*25*5
constexpr int G_   = 64;
constexpr int A_   = 5;
constexpr int POSN = 16;
constexpr int TOTN = 64;

constexpr int CLS_OFF = 0;
constexpr int BT_OFF  = 400000;   // B*A*625
constexpr int BW_OFF  = 2000000;
constexpr int MO_OFF  = 2400000;
}

__device__ __forceinline__ float area_f(float x0, float y0, float x1, float y1) {
#pragma clang fp contract(off)
  return ((x1 - x0) + 1.0f) * ((y1 - y0) + 1.0f);
}

// inter and den=(aarea+garea)-inter with numpy's exact op order.
__device__ __forceinline__ float2 inter_den_f(float a0, float a1, float a2,
                                              float a3, float aarea, float g0,
                                              float g1, float g2, float g3,
                                              float garea) {
#pragma clang fp contract(off)
  float ix = (fminf(a2, g2) - fmaxf(a0, g0)) + 1.0f;
  float iy = (fminf(a3, g3) - fmaxf(a1, g1)) + 1.0f;
  ix = fmaxf(ix, 0.0f);
  iy = fmaxf(iy, 0.0f);
  float inter = ix * iy;
  float den = (aarea + garea) - inter;
  return make_float2(inter, den);
}

// exact real-quotient compare: In/Dn > Ic/Dc (all D > 0; 24-bit products exact)
__device__ __forceinline__ bool q_gt(float In, float Dn, float Ic, float Dc) {
  return (double)In * (double)Dc > (double)Ic * (double)Dn;
}

// ---- K1: gt_max + packed per-(b,g) record; 2 cols/wave; zero poscnt -------
// 4096 waves (1024 blk x 256 thr); wave w -> (b, g0) and (b, g0+1).
// gtpacked[(b*64+g)*8] = {x0,y0,x1,y1, garea, gtmax_adj, 0,0}
__global__ __launch_bounds__(256) void k1_gtmax(
    const float* __restrict__ gt,       // (128,64,4)
    const float* __restrict__ anchors,  // (3125,4)
    float* __restrict__ gtpacked,       // (128,64,8)
    int* __restrict__ poscnt) {
#pragma clang fp contract(off)
  if (blockIdx.x == 0 && threadIdx.x == 0) poscnt[0] = 0;

  const int t    = threadIdx.x;
  const int lane = t & 63;
  const int w    = blockIdx.x * 4 + (t >> 6);  // 0..4095
  const int p0   = w * 2;
  const int b    = p0 >> 6;
  const int g0   = p0 & 63;  // even

  const float4 gg0 = ((const float4*)gt)[b * G_ + g0];
  const float4 gg1 = ((const float4*)gt)[b * G_ + g0 + 1];
  const float ga0 = area_f(gg0.x, gg0.y, gg0.z, gg0.w);
  const float ga1 = area_f(gg1.x, gg1.y, gg1.z, gg1.w);

  // running max as (I,D): q = I/D; init 0/1 == iou 0 (iou >= 0 always)
  float I0 = 0.0f, D0 = 1.0f, I1 = 0.0f, D1 = 1.0f;
#pragma unroll 4
  for (int i = 0; i < 48; ++i) {
    const int n = i * 64 + lane;  // per-lane coalesced
    const float4 aa = ((const float4*)anchors)[n];
    const float aarea = area_f(aa.x, aa.y, aa.z, aa.w);
    const float2 e0 = inter_den_f(aa.x, aa.y, aa.z, aa.w, aarea,
                                  gg0.x, gg0.y, gg0.z, gg0.w, ga0);
    const float2 e1 = inter_den_f(aa.x, aa.y, aa.z, aa.w, aarea,
                                  gg1.x, gg1.y, gg1.z, gg1.w, ga1);
    if (q_gt(e0.x, e0.y, I0, D0)) { I0 = e0.x; D0 = e0.y; }
    if (q_gt(e1.x, e1.y, I1, D1)) { I1 = e1.x; D1 = e1.y; }
  }
  {
    const int n = 48 * 64 + lane;
    if (n < N_) {
      const float4 aa = ((const float4*)anchors)[n];
      const float aarea = area_f(aa.x, aa.y, aa.z, aa.w);
      const float2 e0 = inter_den_f(aa.x, aa.y, aa.z, aa.w, aarea,
                                    gg0.x, gg0.y, gg0.z, gg0.w, ga0);
      const float2 e1 = inter_den_f(aa.x, aa.y, aa.z, aa.w, aarea,
                                    gg1.x, gg1.y, gg1.z, gg1.w, ga1);
      if (q_gt(e0.x, e0.y, I0, D0)) { I0 = e0.x; D0 = e0.y; }
      if (q_gt(e1.x, e1.y, I1, D1)) { I1 = e1.x; D1 = e1.y; }
    }
  }
  // butterfly reduce under the exact-quotient total order (rounding monotone
  // => final rounded quotient == numpy's max of rounded quotients).
#pragma unroll
  for (int off = 32; off > 0; off >>= 1) {
    const float Io0 = __shfl_xor(I0, off, 64), Do0 = __shfl_xor(D0, off, 64);
    const float Io1 = __shfl_xor(I1, off, 64), Do1 = __shfl_xor(D1, off, 64);
    if (q_gt(Io0, Do0, I0, D0)) { I0 = Io0; D0 = Do0; }
    if (q_gt(Io1, Do1, I1, D1)) { I1 = Io1; D1 = Do1; }
  }
  if (lane == 0) {
    const float q0 = I0 / D0;  // IEEE f32 divide == numpy rounding
    const float q1 = I1 / D1;
    float4* gp = (float4*)gtpacked;
    gp[(b * G_ + g0) * 2 + 0] = gg0;
    gp[(b * G_ + g0) * 2 + 1] =
        make_float4(ga0, (q0 == 0.0f) ? 1e-5f : q0, 0.0f, 0.0f);
    gp[(b * G_ + g0 + 1) * 2 + 0] = gg1;
    gp[(b * G_ + g0 + 1) * 2 + 1] =
        make_float4(ga1, (q1 == 0.0f) ? 1e-5f : q1, 0.0f, 0.0f);
  }
}

// ---- K2: per-anchor row -> cls0, bt, max_ov, poscnt -----------------------
// Grid (13, 128), 256 thr, 1 anchor/thread. No LDS/barriers; uniform s_load
// inner loop; wave-uniform zero-overlap skip around the IEEE divide.
__global__ __launch_bounds__(256) void k2_anchor(
    const float* __restrict__ anchors, const float* __restrict__ gtpacked,
    float* __restrict__ out, int* __restrict__ cls0,
    int* __restrict__ poscnt) {
#pragma clang fp contract(off)
  const int b = blockIdx.y;
  const int t = threadIdx.x;
  const int n = blockIdx.x * 256 + t;
  if (n >= N_) return;  // no barriers below — legal

  const float4 aa = ((const float4*)anchors)[n];
  const float aw = (aa.z - aa.x) + 1.0f;
  const float ah = (aa.w - aa.y) + 1.0f;
  const float aarea = aw * ah;  // same op order as area_f

  const float4* __restrict__ gp = (const float4*)gtpacked;
  const int gbase = b * G_ * 2;  // block-uniform

  float best = -1.0f;
  int barg = 0;
  int keep = 0;
#pragma unroll 4
  for (int g = 0; g < G_; ++g) {
    const float4 gg = gp[gbase + g * 2 + 0];  // uniform -> s_load_dwordx4
    const float4 ge = gp[gbase + g * 2 + 1];  // uniform -> s_load_dwordx4
    const float2 e = inter_den_f(aa.x, aa.y, aa.z, aa.w, aarea,
                                 gg.x, gg.y, gg.z, gg.w, ge.x);
    if (__ballot(e.x > 0.0f) != 0ull) {   // wave-uniform: any lane overlaps?
      const float v = e.x / e.y;          // IEEE, bit-exact vs numpy
      if (v > best) { best = v; barg = g; }  // first-occurrence argmax
      keep |= (v == ge.y);                   // bit-exact vs K1
    } else {
      // all lanes: v == +0.0 exactly. keep-term impossible (ge.y >= 1e-5).
      if (best < 0.0f) { best = 0.0f; barg = g; }  // only fires at g==0
    }
  }

  int cc = -1;
  if (best >= 0.6f) cc = 1;
  if (best <= 0.3f) cc = 0;
  if (keep) cc = 1;
  cls0[b * N_ + n] = cc;  // coalesced

  if (b == B_ - 1) {  // wave-uniform branch; inactive lanes excluded
    const unsigned long long m = __ballot(cc == 1);
    if ((t & 63) == 0 && m != 0ull) atomicAdd(poscnt, (int)__popcll(m));
  }

  const float4 mm = gp[gbase + barg * 2];  // divergent, L1/L2-hot
  const float gw = (mm.z - mm.x) + 1.0f;
  const float gh = (mm.w - mm.y) + 1.0f;
  const float acx = aa.x + 0.5f * aw;
  const float acy = aa.y + 0.5f * ah;
  const float gcx = mm.x + 0.5f * gw;
  const float gcy = mm.y + 0.5f * gh;
  const float dx = (gcx - acx) / aw;
  const float dy = (gcy - acy) / ah;
  const float dw = __logf(gw / aw);  // threshold 0.12 abs — fast log fine
  const float dh = __logf(gh / ah);

  // layout: n = (y*25 + x)*5 + a ; spatial index sp = n/5
  const int a = n % A_;
  const int sp = n / A_;

  float* __restrict__ out_bt = out + BT_OFF;
  const int btb = ((b * 4 + 0) * A_ + a) * 625 + sp;
  out_bt[btb + 0 * A_ * 625] = dx;
  out_bt[btb + 1 * A_ * 625] = dy;
  out_bt[btb + 2 * A_ * 625] = dw;
  out_bt[btb + 3 * A_ * 625] = dh;

  out[MO_OFF + b * N_ + n] = best;  // coalesced
}

// ---- K3: per-batch caps (first 16 pos / first 64 neg) + cls + bw ----------
__global__ __launch_bounds__(256) void k3_caps_bw(
    float* __restrict__ out, const int* __restrict__ cls0,
    const int* __restrict__ poscnt) {
  const int b = blockIdx.x;
  const int t = threadIdx.x;
  const int lane = t & 63;
  const int wid = t >> 6;
  __shared__ int s_c[N_];  // cls0 (int), then capped cls (float bits)
  __shared__ int s_w[4];   // per-wave packed totals

  // coalesced stage-in
#pragma unroll
  for (int k = 0; k < 13; ++k) {
    const int i = k * 256 + t;
    if (i < N_) s_c[i] = cls0[b * N_ + i];
  }
  __syncthreads();

  const int n0 = t * 13;
  int cvals[13];
  int myp = 0, myn = 0;
#pragma unroll
  for (int k = 0; k < 13; ++k) {
    const int n = n0 + k;
    int cc = -1;
    if (n < N_) {
      cc = s_c[n];
      if (cc == 1) ++myp;
      else if (cc == 0) ++myn;
    }
    cvals[k] = cc;
  }

  // packed (pos<<16 | neg) inclusive wave scan; totals < 65536 => no carry
  const int pack = (myp << 16) | myn;
  int inc = pack;
#pragma unroll
  for (int off = 1; off < 64; off <<= 1) {
    const int v = __shfl_up(inc, off, 64);
    if (lane >= off) inc += v;
  }
  if (lane == 63) s_w[wid] = inc;
  __syncthreads();
  int wpre = 0;
  for (int j = 0; j < wid; ++j) wpre += s_w[j];
  const int excl = wpre + inc - pack;  // exclusive prefix across block
  int runp = excl >> 16;
  int runn = excl & 0xffff;

#pragma unroll
  for (int k = 0; k < 13; ++k) {
    const int n = n0 + k;
    if (n >= N_) break;
    int cc = cvals[k];
    if (cc == 1) {
      if (++runp > POSN) cc = -1;
    } else if (cc == 0) {
      if (++runn > TOTN) cc = -1;
    }
    s_c[n] = __float_as_int((float)cc);  // own slot, no race
  }
  __syncthreads();

  // pos_num = min(pre-cap positives of batch 127, 16); bw = cls==1 ? 1/p : 0
  const int pc = poscnt[0];
  const float inv = 1.0f / (float)((pc < POSN) ? pc : POSN);

  // coalesced transposed write: o = a*625 + spat, n = spat*5 + a
  // (LDS gather stride 5 dwords: gcd(5,32)=1 -> conflict-free)
#pragma unroll
  for (int k = 0; k < 13; ++k) {
    const int o = k * 256 + t;
    if (o < N_) {
      const int a  = o / 625;
      const int sp = o % 625;
      const float v = __int_as_float(s_c[sp * 5 + a]);
      out[CLS_OFF + b * N_ + o] = v;
      out[BW_OFF + b * N_ + o] = (v == 1.0f) ? inv : 0.0f;
    }
  }
}

extern "C" void kernel_launch(void* const* d_in, const int* in_sizes, int n_in,
                              void* d_out, int out_size, void* d_ws,
                              size_t ws_size, hipStream_t stream) {
  const float* gt = (const float*)d_in[0];       // (128,64,4)
  const float* anchors = (const float*)d_in[1];  // (3125,4)
  float* out = (float*)d_out;
  int* poscnt = (int*)d_ws;                      // [0]
  float* gtpacked = (float*)d_ws + 64;           // 128*64*8 floats, 16B-aligned
  int* cls0 = (int*)d_ws + 64 + B_ * G_ * 8;     // 400000 ints

  // Stream ordering: K1 zeroes poscnt & fills gtpacked; K2 consumes gtpacked,
  // produces cls0+poscnt; K3 consumes cls0+poscnt. No memsets needed.
  k1_gtmax<<<1024, 256, 0, stream>>>(gt, anchors, gtpacked, poscnt);
  k2_anchor<<<dim3(13, B_), 256, 0, stream>>>(anchors, gtpacked, out, cls0,
                                              poscnt);
  k3_caps_bw<<<B_, 256, 0, stream>>>(out, cls0, poscnt);
}